// Round 15
// baseline (132.742 us; speedup 1.0000x reference)
//
#include <hip/hip_runtime.h>

#define NSTEPS 80
#define BATCH  65536
#define NIN    20
#define NHID   10
#define NOUT   2

// Load one timestep's 20 floats for this batch element (80 B, 16B-aligned).
__device__ __forceinline__ void load_x20(float* __restrict__ dst,
                                         const float* __restrict__ src) {
#pragma unroll
  for (int k = 0; k < NIN; k += 4) {
    const float4 v = *reinterpret_cast<const float4*>(src + k);
    dst[k + 0] = v.x; dst[k + 1] = v.y; dst[k + 2] = v.z; dst[k + 3] = v.w;
  }
}

// One SNN timestep.
//   dot: zero-init, ascending-k fused FMA, bias added AFTER (BLAS order).
//   update: fmaf(0.5, mem, cur) - reset   (0.5*mem exact -> == unfused chain)
//   spike: mem >= 1.0f  -- ">=" IS THE POINT: the np reference's Heaviside
//   fires at exactly-zero argument (np.heaviside(x,1) / x>=0 semantics).
//   mem-1 is Sterbenz-exact near 1, so (mem>=1) == (mem-1>=0). This differs
//   from strict ">" only when mem == 1.0f exactly -- the bitwise-stable
//   event class that made all 7 prior ordering variants fail identically.
__device__ __forceinline__ void snn_step(
    const float (&xb)[NIN],
    const float (&w1)[NHID][NIN], const float (&bb1)[NHID],
    const float (&w2)[NOUT][NHID], const float (&bb2)[NOUT],
    float (&mem1)[NHID], float (&mem2)[NOUT],
    float2& spk_out, float2& mem_out)
{
  float spk1[NHID];
#pragma unroll
  for (int j = 0; j < NHID; ++j) {
    float acc = 0.0f;
#pragma unroll
    for (int k = 0; k < NIN; ++k) acc = fmaf(xb[k], w1[j][k], acc);
    const float cur = acc + bb1[j];
    const float reset = (mem1[j] >= 1.0f) ? 1.0f : 0.0f;  // spike of OLD mem1
    const float m = fmaf(0.5f, mem1[j], cur) - reset;
    mem1[j] = m;
    spk1[j] = (m >= 1.0f) ? 1.0f : 0.0f;
  }
#pragma unroll
  for (int o = 0; o < NOUT; ++o) {
    float acc = 0.0f;
#pragma unroll
    for (int j = 0; j < NHID; ++j) acc = fmaf(spk1[j], w2[o][j], acc);
    const float cur = acc + bb2[o];
    const float reset = (mem2[o] >= 1.0f) ? 1.0f : 0.0f;
    mem2[o] = fmaf(0.5f, mem2[o], cur) - reset;
  }
  spk_out = make_float2((mem2[0] >= 1.0f) ? 1.0f : 0.0f,
                        (mem2[1] >= 1.0f) ? 1.0f : 0.0f);
  mem_out = make_float2(mem2[0], mem2[1]);
}

// One thread per batch element; weights in VGPRs (fully unrolled indices);
// x[t+1] software-prefetched into a double buffer while computing step t.
// 1024 waves total => 1 wave/SIMD; launch_bounds(256,1) gives the full
// VGPR budget so the working set never spills.
__global__ __launch_bounds__(256, 1)
void snn_forward(const float* __restrict__ x,
                 const float* __restrict__ W1, const float* __restrict__ B1,
                 const float* __restrict__ W2, const float* __restrict__ B2,
                 float* __restrict__ out)
{
  const int b = blockIdx.x * blockDim.x + threadIdx.x;

  float w1[NHID][NIN];
#pragma unroll
  for (int j = 0; j < NHID; ++j)
#pragma unroll
    for (int k = 0; k < NIN; k += 4) {
      const float4 v = *reinterpret_cast<const float4*>(W1 + j * NIN + k);
      w1[j][k] = v.x; w1[j][k + 1] = v.y; w1[j][k + 2] = v.z; w1[j][k + 3] = v.w;
    }
  float bb1[NHID];
#pragma unroll
  for (int j = 0; j < NHID; ++j) bb1[j] = B1[j];
  float w2[NOUT][NHID];
#pragma unroll
  for (int o = 0; o < NOUT; ++o)
#pragma unroll
    for (int j = 0; j < NHID; ++j) w2[o][j] = W2[o * NHID + j];
  float bb2[NOUT];
#pragma unroll
  for (int o = 0; o < NOUT; ++o) bb2[o] = B2[o];

  float mem1[NHID];
#pragma unroll
  for (int j = 0; j < NHID; ++j) mem1[j] = 0.0f;
  float mem2[NOUT] = {0.0f, 0.0f};

  const float* xp = x + (size_t)b * NIN;
  const size_t step_stride = (size_t)BATCH * NIN;
  float* __restrict__ spk_base = out;
  float* __restrict__ mem_base = out + (size_t)NSTEPS * BATCH * NOUT;

  float bufA[NIN], bufB[NIN];
  load_x20(bufA, xp);  // t = 0

  for (int tt = 0; tt < NSTEPS; tt += 2) {
    load_x20(bufB, xp + (size_t)(tt + 1) * step_stride);  // prefetch t+1

    float2 s0, m0;
    snn_step(bufA, w1, bb1, w2, bb2, mem1, mem2, s0, m0);
    {
      const size_t idx = ((size_t)tt * BATCH + b) * NOUT;
      *reinterpret_cast<float2*>(spk_base + idx) = s0;
      *reinterpret_cast<float2*>(mem_base + idx) = m0;
    }

    if (tt + 2 < NSTEPS)
      load_x20(bufA, xp + (size_t)(tt + 2) * step_stride); // prefetch t+2

    float2 s1, m1;
    snn_step(bufB, w1, bb1, w2, bb2, mem1, mem2, s1, m1);
    {
      const size_t idx = ((size_t)(tt + 1) * BATCH + b) * NOUT;
      *reinterpret_cast<float2*>(spk_base + idx) = s1;
      *reinterpret_cast<float2*>(mem_base + idx) = m1;
    }
  }
}

extern "C" void kernel_launch(void* const* d_in, const int* in_sizes, int n_in,
                              void* d_out, int out_size, void* d_ws, size_t ws_size,
                              hipStream_t stream) {
  (void)in_sizes; (void)n_in; (void)d_ws; (void)ws_size; (void)out_size;
  const float* x  = (const float*)d_in[0];
  const float* W1 = (const float*)d_in[1];
  const float* B1 = (const float*)d_in[2];
  const float* W2 = (const float*)d_in[3];
  const float* B2 = (const float*)d_in[4];
  float* out = (float*)d_out;

  dim3 grid(BATCH / 256), block(256);
  snn_forward<<<grid, block, 0, stream>>>(x, W1, B1, W2, B2, out);
}

// Round 16
// 104.414 us; speedup vs baseline: 1.2713x; 1.2713x over previous
//
#include <hip/hip_runtime.h>

#define NSTEPS 80
#define BATCH  65536
#define NIN    20
#define NHID   10
#define NOUT   2

// Load one timestep's 20 floats for this batch element (80 B, 16B-aligned).
__device__ __forceinline__ void load_x20(float* __restrict__ dst,
                                         const float* __restrict__ src) {
#pragma unroll
  for (int k = 0; k < NIN; k += 4) {
    const float4 v = *reinterpret_cast<const float4*>(src + k);
    dst[k + 0] = v.x; dst[k + 1] = v.y; dst[k + 2] = v.z; dst[k + 3] = v.w;
  }
}

// Non-temporal 8B store (spk/mem float2) — output is write-once, never
// re-read by the kernel; NT keeps the 84 MB write stream out of L2 so the
// streamed x isn't evicted.
__device__ __forceinline__ void st_nt2(float* p, float2 v) {
  union { float2 f; double d; } u; u.f = v;
  __builtin_nontemporal_store(u.d, reinterpret_cast<double*>(p));
}

// One SNN timestep — VERIFIED NUMERICS (round 15), do not modify:
//   dot: zero-init, ascending-k fused FMA, bias added AFTER.
//   update: fmaf(0.5, mem, cur) - reset   (0.5*mem exact)
//   spike: mem >= 1.0f   (np.heaviside(x,1): fires at exactly-zero argument;
//          mem-1 Sterbenz-exact near 1 so (mem>=1) == (mem-1>=0))
__device__ __forceinline__ void snn_step(
    const float (&xb)[NIN],
    const float (&w1)[NHID][NIN], const float (&bb1)[NHID],
    const float (&w2)[NOUT][NHID], const float (&bb2)[NOUT],
    float (&mem1)[NHID], float (&mem2)[NOUT],
    float2& spk_out, float2& mem_out)
{
  float spk1[NHID];
#pragma unroll
  for (int j = 0; j < NHID; ++j) {
    float acc = 0.0f;
#pragma unroll
    for (int k = 0; k < NIN; ++k) acc = fmaf(xb[k], w1[j][k], acc);
    const float cur = acc + bb1[j];
    const float reset = (mem1[j] >= 1.0f) ? 1.0f : 0.0f;  // spike of OLD mem1
    const float m = fmaf(0.5f, mem1[j], cur) - reset;
    mem1[j] = m;
    spk1[j] = (m >= 1.0f) ? 1.0f : 0.0f;
  }
#pragma unroll
  for (int o = 0; o < NOUT; ++o) {
    float acc = 0.0f;
#pragma unroll
    for (int j = 0; j < NHID; ++j) acc = fmaf(spk1[j], w2[o][j], acc);
    const float cur = acc + bb2[o];
    const float reset = (mem2[o] >= 1.0f) ? 1.0f : 0.0f;
    mem2[o] = fmaf(0.5f, mem2[o], cur) - reset;
  }
  spk_out = make_float2((mem2[0] >= 1.0f) ? 1.0f : 0.0f,
                        (mem2[1] >= 1.0f) ? 1.0f : 0.0f);
  mem_out = make_float2(mem2[0], mem2[1]);
}

// One thread per batch element. Occupancy is structurally 1 wave/SIMD
// (65536 threads / 1024 SIMDs), so memory-level parallelism must come from
// prefetch depth: 4 rotating x-buffers keep ~3 steps (15 KB/wave, 60 KB/CU)
// in flight — Little's law needs >=20 KB/CU at 6.3 TB/s & ~2000 cyc latency.
// VGPR ~360 of 512 at launch_bounds(256,1): no spill.
__global__ __launch_bounds__(256, 1)
void snn_forward(const float* __restrict__ x,
                 const float* __restrict__ W1, const float* __restrict__ B1,
                 const float* __restrict__ W2, const float* __restrict__ B2,
                 float* __restrict__ out)
{
  const int b = blockIdx.x * blockDim.x + threadIdx.x;

  float w1[NHID][NIN];
#pragma unroll
  for (int j = 0; j < NHID; ++j)
#pragma unroll
    for (int k = 0; k < NIN; k += 4) {
      const float4 v = *reinterpret_cast<const float4*>(W1 + j * NIN + k);
      w1[j][k] = v.x; w1[j][k + 1] = v.y; w1[j][k + 2] = v.z; w1[j][k + 3] = v.w;
    }
  float bb1[NHID];
#pragma unroll
  for (int j = 0; j < NHID; ++j) bb1[j] = B1[j];
  float w2[NOUT][NHID];
#pragma unroll
  for (int o = 0; o < NOUT; ++o)
#pragma unroll
    for (int j = 0; j < NHID; ++j) w2[o][j] = W2[o * NHID + j];
  float bb2[NOUT];
#pragma unroll
  for (int o = 0; o < NOUT; ++o) bb2[o] = B2[o];

  float mem1[NHID];
#pragma unroll
  for (int j = 0; j < NHID; ++j) mem1[j] = 0.0f;
  float mem2[NOUT] = {0.0f, 0.0f};

  const size_t ss = (size_t)BATCH * NIN;        // x floats per timestep
  const size_t os = (size_t)BATCH * NOUT;       // out floats per timestep
  const float* xp = x + (size_t)b * NIN;
  float* sp = out + (size_t)b * NOUT;                       // spk2_rec cursor
  float* mp = sp + (size_t)NSTEPS * BATCH * NOUT;           // mem2_rec cursor

  float B0[NIN], B1b[NIN], B2b[NIN], B3[NIN];
  load_x20(B0,  xp);
  load_x20(B1b, xp + 1 * ss);
  load_x20(B2b, xp + 2 * ss);

#define SNN_STEP_EMIT(BUF)                                          \
  {                                                                 \
    float2 s_, m_;                                                  \
    snn_step(BUF, w1, bb1, w2, bb2, mem1, mem2, s_, m_);            \
    st_nt2(sp, s_); st_nt2(mp, m_);                                 \
    sp += os; mp += os;                                             \
  }

  for (int t = 0; t < NSTEPS; t += 4) {
    if (t + 3 < NSTEPS) load_x20(B3,  xp + (size_t)(t + 3) * ss);
    SNN_STEP_EMIT(B0);
    if (t + 4 < NSTEPS) load_x20(B0,  xp + (size_t)(t + 4) * ss);
    SNN_STEP_EMIT(B1b);
    if (t + 5 < NSTEPS) load_x20(B1b, xp + (size_t)(t + 5) * ss);
    SNN_STEP_EMIT(B2b);
    if (t + 6 < NSTEPS) load_x20(B2b, xp + (size_t)(t + 6) * ss);
    SNN_STEP_EMIT(B3);
  }
#undef SNN_STEP_EMIT
}

extern "C" void kernel_launch(void* const* d_in, const int* in_sizes, int n_in,
                              void* d_out, int out_size, void* d_ws, size_t ws_size,
                              hipStream_t stream) {
  (void)in_sizes; (void)n_in; (void)d_ws; (void)ws_size; (void)out_size;
  const float* x  = (const float*)d_in[0];
  const float* W1 = (const float*)d_in[1];
  const float* B1 = (const float*)d_in[2];
  const float* W2 = (const float*)d_in[3];
  const float* B2 = (const float*)d_in[4];
  float* out = (float*)d_out;

  dim3 grid(BATCH / 256), block(256);
  snn_forward<<<grid, block, 0, stream>>>(x, W1, B1, W2, B2, out);
}

// Round 17
// 99.923 us; speedup vs baseline: 1.3284x; 1.0449x over previous
//
#include <hip/hip_runtime.h>

#define NSTEPS 80
#define BATCH  65536
#define NIN    20
#define NHID   10
#define NOUT   2
#define NH2    5      // hidden neurons per lane (NHID/2)

// Load one timestep's 20 floats (80 B, 16B-aligned). Lane pairs (b,h=0/1)
// issue IDENTICAL addresses -> VMEM coalescer dedups; HBM traffic unchanged.
__device__ __forceinline__ void load_x20(float* __restrict__ dst,
                                         const float* __restrict__ src) {
#pragma unroll
  for (int k = 0; k < NIN; k += 4) {
    const float4 v = *reinterpret_cast<const float4*>(src + k);
    dst[k + 0] = v.x; dst[k + 1] = v.y; dst[k + 2] = v.z; dst[k + 3] = v.w;
  }
}

// Non-temporal 8B store — outputs are write-once; keep them out of L2.
__device__ __forceinline__ void st_nt2(float* p, float2 v) {
  union { float2 f; double d; } u; u.f = v;
  __builtin_nontemporal_store(u.d, reinterpret_cast<double*>(p));
}

// One SNN timestep, 2 lanes per batch element (split by hidden neuron).
// VERIFIED NUMERICS (R15) preserved bit-exactly:
//   - each lane runs the SAME zero-init ascending-k fused-FMA chain per
//     neuron (5 neurons/lane), bias added after
//   - spikes exchanged via shfl_xor (exact bits), layer-2 chain j=0..9
//     ascending, computed redundantly+identically on both lanes
//   - update fmaf(0.5,mem,cur)-reset; spike: mem >= 1.0f (heaviside(0)=1)
__device__ __forceinline__ void snn_step2(
    const float (&xb)[NIN], int h,
    const float (&w1)[NH2][NIN], const float (&bb1)[NH2],
    const float (&w2)[NOUT][NHID], const float (&bb2)[NOUT],
    float (&mem1)[NH2], float (&mem2)[NOUT],
    float2& spk_out, float2& mem_out)
{
  // layer 1: own 5 hidden neurons, full 20-FMA chain each
  float a[NH2];
#pragma unroll
  for (int jj = 0; jj < NH2; ++jj) {
    float acc = 0.0f;
#pragma unroll
    for (int k = 0; k < NIN; ++k) acc = fmaf(xb[k], w1[jj][k], acc);
    const float cur = acc + bb1[jj];
    const float reset = (mem1[jj] >= 1.0f) ? 1.0f : 0.0f;
    const float m = fmaf(0.5f, mem1[jj], cur) - reset;
    mem1[jj] = m;
    a[jj] = (m >= 1.0f) ? 1.0f : 0.0f;
  }
  // exchange the partner lane's 5 spikes (lane^1 == same element, other half)
  float o5[NH2];
#pragma unroll
  for (int jj = 0; jj < NH2; ++jj) o5[jj] = __shfl_xor(a[jj], 1);
  // assemble spk1[0..9] in canonical order (h uniform per lane -> cndmask)
  float s[NHID];
#pragma unroll
  for (int j = 0; j < NH2; ++j)  s[j]       = h ? o5[j] : a[j];
#pragma unroll
  for (int j = 0; j < NH2; ++j)  s[NH2 + j] = h ? a[j]  : o5[j];
  // layer 2: identical on both lanes (deterministic)
#pragma unroll
  for (int o = 0; o < NOUT; ++o) {
    float acc = 0.0f;
#pragma unroll
    for (int j = 0; j < NHID; ++j) acc = fmaf(s[j], w2[o][j], acc);
    const float cur = acc + bb2[o];
    const float reset = (mem2[o] >= 1.0f) ? 1.0f : 0.0f;
    mem2[o] = fmaf(0.5f, mem2[o], cur) - reset;
  }
  spk_out = make_float2((mem2[0] >= 1.0f) ? 1.0f : 0.0f,
                        (mem2[1] >= 1.0f) ? 1.0f : 0.0f);
  mem_out = make_float2(mem2[0], mem2[1]);
}

// Two threads per batch element -> 2048 waves = 2 waves/SIMD (vs 1 before):
// SIMD-level interleaving hides VALU + residual latency. ~230 VGPR fits
// launch_bounds(256,2). 3 rotating x-buffers (distance >=2 steps in flight).
__global__ __launch_bounds__(256, 2)
void snn_forward2(const float* __restrict__ x,
                  const float* __restrict__ W1, const float* __restrict__ B1,
                  const float* __restrict__ W2, const float* __restrict__ B2,
                  float* __restrict__ out)
{
  const int i = blockIdx.x * blockDim.x + threadIdx.x;   // 0..2*BATCH-1
  const int b = i >> 1;
  const int h = i & 1;
  const int j0 = NH2 * h;

  float w1[NH2][NIN];
#pragma unroll
  for (int jj = 0; jj < NH2; ++jj)
#pragma unroll
    for (int k = 0; k < NIN; k += 4) {
      const float4 v = *reinterpret_cast<const float4*>(W1 + (j0 + jj) * NIN + k);
      w1[jj][k] = v.x; w1[jj][k + 1] = v.y; w1[jj][k + 2] = v.z; w1[jj][k + 3] = v.w;
    }
  float bb1[NH2];
#pragma unroll
  for (int jj = 0; jj < NH2; ++jj) bb1[jj] = B1[j0 + jj];
  float w2[NOUT][NHID];
#pragma unroll
  for (int o = 0; o < NOUT; ++o)
#pragma unroll
    for (int j = 0; j < NHID; ++j) w2[o][j] = W2[o * NHID + j];
  float bb2[NOUT];
#pragma unroll
  for (int o = 0; o < NOUT; ++o) bb2[o] = B2[o];

  float mem1[NH2];
#pragma unroll
  for (int jj = 0; jj < NH2; ++jj) mem1[jj] = 0.0f;
  float mem2[NOUT] = {0.0f, 0.0f};

  const size_t ss = (size_t)BATCH * NIN;
  const size_t os = (size_t)BATCH * NOUT;
  const float* xp = x + (size_t)b * NIN;
  // h=0 writes spk2_rec, h=1 writes mem2_rec (one 8B NT store per step)
  float* op = out + (h ? (size_t)NSTEPS * BATCH * NOUT : 0) + (size_t)b * NOUT;

  float A[NIN], Bb[NIN], C[NIN];
  load_x20(A,  xp);
  load_x20(Bb, xp + ss);

#define SNN_STEP_EMIT(BUF)                                           \
  {                                                                  \
    float2 s_, m_;                                                   \
    snn_step2(BUF, h, w1, bb1, w2, bb2, mem1, mem2, s_, m_);         \
    st_nt2(op, h ? m_ : s_);                                         \
    op += os;                                                        \
  }

  // 26 iters cover t=0..77 (all prefetch indices <= 79: no guards needed)
  for (int t = 0; t < 78; t += 3) {
    load_x20(C,  xp + (size_t)(t + 2) * ss);
    SNN_STEP_EMIT(A);
    load_x20(A,  xp + (size_t)(t + 3) * ss);
    SNN_STEP_EMIT(Bb);
    load_x20(Bb, xp + (size_t)(t + 4) * ss);
    SNN_STEP_EMIT(C);
  }
  // tail: steps 78 (in A), 79 (in Bb)
  SNN_STEP_EMIT(A);
  SNN_STEP_EMIT(Bb);
#undef SNN_STEP_EMIT
}

extern "C" void kernel_launch(void* const* d_in, const int* in_sizes, int n_in,
                              void* d_out, int out_size, void* d_ws, size_t ws_size,
                              hipStream_t stream) {
  (void)in_sizes; (void)n_in; (void)d_ws; (void)ws_size; (void)out_size;
  const float* x  = (const float*)d_in[0];
  const float* W1 = (const float*)d_in[1];
  const float* B1 = (const float*)d_in[2];
  const float* W2 = (const float*)d_in[3];
  const float* B2 = (const float*)d_in[4];
  float* out = (float*)d_out;

  dim3 grid(2 * BATCH / 256), block(256);
  snn_forward2<<<grid, block, 0, stream>>>(x, W1, B1, W2, B2, out);
}

// Round 18
// 96.289 us; speedup vs baseline: 1.3786x; 1.0377x over previous
//
#include <hip/hip_runtime.h>

#define NSTEPS 80
#define BATCH  65536
#define NIN    20
#define NHID   10
#define NOUT   2
#define NH2    5      // hidden neurons per lane (NHID/2)
#define NW     12     // floats loaded per lane per step (3 x float4 window)

// Non-temporal 8B store — outputs are write-once; keep them out of L2.
__device__ __forceinline__ void st_nt2(float* p, float2 v) {
  union { float2 f; double d; } u; u.f = v;
  __builtin_nontemporal_store(u.d, reinterpret_cast<double*>(p));
}

// Windowed x load: lane h of a pair loads 12 of the row's 20 floats.
//   h=0: k0..11 (row+0), h=1: k8..19 (row+32B). 3 float4 each ->
//   6 VMEM instrs per pair per step instead of 10 (no duplicate addresses).
__device__ __forceinline__ void load_x12(float* __restrict__ W,
                                         const float* __restrict__ row, int h) {
  const float* src = row + h * 8;   // h=1 starts at k=8
#pragma unroll
  for (int c = 0; c < 3; ++c) {
    const float4 v = *reinterpret_cast<const float4*>(src + 4 * c);
    W[4 * c + 0] = v.x; W[4 * c + 1] = v.y; W[4 * c + 2] = v.z; W[4 * c + 3] = v.w;
  }
}

// Reassemble the full 20-float row from own window + partner's window.
// 12 shfl_xor(.,1) (DPP pair swap) move bits; h-selects pick source.
// Values are MOVED, never recomputed -> bit-identical to verified numerics.
__device__ __forceinline__ void gather_x20(float (&xb)[NIN],
                                           const float (&W)[NW], int h) {
  float R[NW];
#pragma unroll
  for (int j = 0; j < NW; ++j) R[j] = __shfl_xor(W[j], 1);
#pragma unroll
  for (int k = 0; k < 8; ++k)  xb[k]      = h ? R[k]     : W[k];      // k0..7
#pragma unroll
  for (int k = 0; k < 4; ++k)  xb[8 + k]  = h ? W[k]     : W[8 + k];  // k8..11
#pragma unroll
  for (int k = 0; k < 4; ++k)  xb[12 + k] = h ? W[4 + k] : R[4 + k];  // k12..15
#pragma unroll
  for (int k = 0; k < 4; ++k)  xb[16 + k] = h ? W[8 + k] : R[8 + k];  // k16..19
}

// One SNN timestep, 2 lanes per batch element (split by hidden neuron).
// VERIFIED NUMERICS (R15) preserved bit-exactly: zero-init ascending-k
// fused-FMA chains, bias after, fmaf(0.5,mem,cur)-reset, spike mem>=1.0f
// (np.heaviside(x,1) fires at exactly-zero argument).
__device__ __forceinline__ void snn_step2(
    const float (&xb)[NIN], int h,
    const float (&w1)[NH2][NIN], const float (&bb1)[NH2],
    const float (&w2)[NOUT][NHID], const float (&bb2)[NOUT],
    float (&mem1)[NH2], float (&mem2)[NOUT],
    float2& spk_out, float2& mem_out)
{
  float a[NH2];
#pragma unroll
  for (int jj = 0; jj < NH2; ++jj) {
    float acc = 0.0f;
#pragma unroll
    for (int k = 0; k < NIN; ++k) acc = fmaf(xb[k], w1[jj][k], acc);
    const float cur = acc + bb1[jj];
    const float reset = (mem1[jj] >= 1.0f) ? 1.0f : 0.0f;
    const float m = fmaf(0.5f, mem1[jj], cur) - reset;
    mem1[jj] = m;
    a[jj] = (m >= 1.0f) ? 1.0f : 0.0f;
  }
  float o5[NH2];
#pragma unroll
  for (int jj = 0; jj < NH2; ++jj) o5[jj] = __shfl_xor(a[jj], 1);
  float s[NHID];
#pragma unroll
  for (int j = 0; j < NH2; ++j)  s[j]       = h ? o5[j] : a[j];
#pragma unroll
  for (int j = 0; j < NH2; ++j)  s[NH2 + j] = h ? a[j]  : o5[j];
#pragma unroll
  for (int o = 0; o < NOUT; ++o) {
    float acc = 0.0f;
#pragma unroll
    for (int j = 0; j < NHID; ++j) acc = fmaf(s[j], w2[o][j], acc);
    const float cur = acc + bb2[o];
    const float reset = (mem2[o] >= 1.0f) ? 1.0f : 0.0f;
    mem2[o] = fmaf(0.5f, mem2[o], cur) - reset;
  }
  spk_out = make_float2((mem2[0] >= 1.0f) ? 1.0f : 0.0f,
                        (mem2[1] >= 1.0f) ? 1.0f : 0.0f);
  mem_out = make_float2(mem2[0], mem2[1]);
}

// 2 threads/elem = 2 waves/SIMD (TLP) + windowed loads (no dup VMEM).
// ~210 VGPR at launch_bounds(256,2); 3 rotating 12-float windows keep
// >=2 steps of x in flight.
__global__ __launch_bounds__(256, 2)
void snn_forward2(const float* __restrict__ x,
                  const float* __restrict__ W1, const float* __restrict__ B1,
                  const float* __restrict__ W2, const float* __restrict__ B2,
                  float* __restrict__ out)
{
  const int i = blockIdx.x * blockDim.x + threadIdx.x;   // 0..2*BATCH-1
  const int b = i >> 1;
  const int h = i & 1;
  const int j0 = NH2 * h;

  float w1[NH2][NIN];
#pragma unroll
  for (int jj = 0; jj < NH2; ++jj)
#pragma unroll
    for (int k = 0; k < NIN; k += 4) {
      const float4 v = *reinterpret_cast<const float4*>(W1 + (j0 + jj) * NIN + k);
      w1[jj][k] = v.x; w1[jj][k + 1] = v.y; w1[jj][k + 2] = v.z; w1[jj][k + 3] = v.w;
    }
  float bb1[NH2];
#pragma unroll
  for (int jj = 0; jj < NH2; ++jj) bb1[jj] = B1[j0 + jj];
  float w2[NOUT][NHID];
#pragma unroll
  for (int o = 0; o < NOUT; ++o)
#pragma unroll
    for (int j = 0; j < NHID; ++j) w2[o][j] = W2[o * NHID + j];
  float bb2[NOUT];
#pragma unroll
  for (int o = 0; o < NOUT; ++o) bb2[o] = B2[o];

  float mem1[NH2];
#pragma unroll
  for (int jj = 0; jj < NH2; ++jj) mem1[jj] = 0.0f;
  float mem2[NOUT] = {0.0f, 0.0f};

  const size_t ss = (size_t)BATCH * NIN;
  const size_t os = (size_t)BATCH * NOUT;
  const float* xp = x + (size_t)b * NIN;
  float* op = out + (h ? (size_t)NSTEPS * BATCH * NOUT : 0) + (size_t)b * NOUT;

  float A[NW], Bb[NW], C[NW];
  load_x12(A,  xp,      h);
  load_x12(Bb, xp + ss, h);

#define SNN_STEP_EMIT(BUF)                                           \
  {                                                                  \
    float xb[NIN];                                                   \
    gather_x20(xb, BUF, h);                                          \
    float2 s_, m_;                                                   \
    snn_step2(xb, h, w1, bb1, w2, bb2, mem1, mem2, s_, m_);          \
    st_nt2(op, h ? m_ : s_);                                         \
    op += os;                                                        \
  }

  // 26 iters cover t=0..77 (prefetch indices <= 79: no guards needed)
  for (int t = 0; t < 78; t += 3) {
    load_x12(C,  xp + (size_t)(t + 2) * ss, h);
    SNN_STEP_EMIT(A);
    load_x12(A,  xp + (size_t)(t + 3) * ss, h);
    SNN_STEP_EMIT(Bb);
    load_x12(Bb, xp + (size_t)(t + 4) * ss, h);
    SNN_STEP_EMIT(C);
  }
  SNN_STEP_EMIT(A);   // t = 78
  SNN_STEP_EMIT(Bb);  // t = 79
#undef SNN_STEP_EMIT
}

extern "C" void kernel_launch(void* const* d_in, const int* in_sizes, int n_in,
                              void* d_out, int out_size, void* d_ws, size_t ws_size,
                              hipStream_t stream) {
  (void)in_sizes; (void)n_in; (void)d_ws; (void)ws_size; (void)out_size;
  const float* x  = (const float*)d_in[0];
  const float* W1 = (const float*)d_in[1];
  const float* B1 = (const float*)d_in[2];
  const float* W2 = (const float*)d_in[3];
  const float* B2 = (const float*)d_in[4];
  float* out = (float*)d_out;

  dim3 grid(2 * BATCH / 256), block(256);
  snn_forward2<<<grid, block, 0, stream>>>(x, W1, B1, W2, B2, out);
}